// Round 13
// baseline (389.608 us; speedup 1.0000x reference)
//
#include <hip/hip_runtime.h>
#include <hip/hip_bf16.h>

constexpr int D = 128;
constexpr int BUCKET_SHIFT = 6;        // 64 rows per bucket
constexpr int BUCKET_CAP_LOG2 = 12;    // 4096 slots per bucket (mean 2048, >40 sigma)
constexpr int BUCKET_CAP = 1 << BUCKET_CAP_LOG2;
constexpr int SEG_SHIFT = 13;          // 8192 source rows per segment = 2MB bf16
constexpr int NSEG = 13;               // ceil(100000 / 8192)
constexpr int BINS_PER_BUCKET = 4 * NSEG * 16;   // (group, seg, rowloc) = 832
constexpr int BINS_PER_WAVE = NSEG * 16;         // 208
typedef __hip_bfloat16 bf16;

// ---------------------------------------------------------------------------
// Fused GEMM + attention partial dots:
//   h0 = relu(x W0^T + b0) [f32]   (+ partial a_self via atomicAdd)
//   h1 = relu(x W1^T + b1) [bf16]  (+ partial a_neigh via atomicAdd)
// a_self / a_neigh hold RAW dots; LeakyReLU + weight fusion happens in k_fuse.
// ---------------------------------------------------------------------------
__global__ __launch_bounds__(256) void k_gemm(
    const float* __restrict__ x,
    const float* __restrict__ W0, const float* __restrict__ b0,
    const float* __restrict__ W1, const float* __restrict__ b1,
    const float* __restrict__ att,
    float* __restrict__ h0, bf16* __restrict__ h1b,
    float* __restrict__ a_self, float* __restrict__ a_neigh, int N)
{
  constexpr int XS_STRIDE = 132;
  constexpr int WS_STRIDE = 68;
  __shared__ float xs_t[64 * XS_STRIDE];
  __shared__ float ws_t[64 * WS_STRIDE];

  const int t  = threadIdx.x;
  const int nb = blockIdx.x;
  const int fb = blockIdx.y;
  const int n0 = nb * 128;

  const float* __restrict__ W    = (fb < 2) ? W0 : W1;
  const float* __restrict__ bias = (fb < 2) ? b0 : b1;
  float* __restrict__ adest      = (fb < 2) ? a_self : a_neigh;
  const int frow0 = (fb & 1) * 64;

  const int tf = t & 15;
  const int tn = t >> 4;

  const int x_nq = t >> 1;
  const int x_kq = t & 1;
  const int w_f  = t >> 2;
  const int w_kq = t & 3;

  float acc[8][4];
#pragma unroll
  for (int i = 0; i < 8; ++i)
#pragma unroll
    for (int j = 0; j < 4; ++j) acc[i][j] = 0.0f;

  const bool x_ok = (n0 + x_nq) < N;
  const float* xrow = x + (size_t)(n0 + x_nq) * D;
  const float* wrow = W + (size_t)(frow0 + w_f) * D;

  for (int c = 0; c < 2; ++c) {
    const int k0 = c * 64;
    if (c) __syncthreads();

#pragma unroll
    for (int i = 0; i < 8; ++i) {
      const int k = x_kq * 32 + i * 4;
      float4 v = x_ok ? *reinterpret_cast<const float4*>(xrow + k0 + k)
                      : make_float4(0.f, 0.f, 0.f, 0.f);
      xs_t[(k + 0) * XS_STRIDE + x_nq] = v.x;
      xs_t[(k + 1) * XS_STRIDE + x_nq] = v.y;
      xs_t[(k + 2) * XS_STRIDE + x_nq] = v.z;
      xs_t[(k + 3) * XS_STRIDE + x_nq] = v.w;
    }
#pragma unroll
    for (int i = 0; i < 4; ++i) {
      const int k = w_kq * 4 + i * 16;
      float4 v = *reinterpret_cast<const float4*>(wrow + k0 + k);
      ws_t[(k + 0) * WS_STRIDE + w_f] = v.x;
      ws_t[(k + 1) * WS_STRIDE + w_f] = v.y;
      ws_t[(k + 2) * WS_STRIDE + w_f] = v.z;
      ws_t[(k + 3) * WS_STRIDE + w_f] = v.w;
    }
    __syncthreads();

#pragma unroll 4
    for (int k = 0; k < 64; ++k) {
      const float4 a0 = *reinterpret_cast<const float4*>(&xs_t[k * XS_STRIDE + tn * 4]);
      const float4 a1 = *reinterpret_cast<const float4*>(&xs_t[k * XS_STRIDE + 64 + tn * 4]);
      const float4 bvec = *reinterpret_cast<const float4*>(&ws_t[k * WS_STRIDE + tf * 4]);
      const float av[8] = {a0.x, a0.y, a0.z, a0.w, a1.x, a1.y, a1.z, a1.w};
      const float bv[4] = {bvec.x, bvec.y, bvec.z, bvec.w};
#pragma unroll
      for (int i = 0; i < 8; ++i)
#pragma unroll
        for (int j = 0; j < 4; ++j)
          acc[i][j] = fmaf(av[i], bv[j], acc[i][j]);
    }
  }

  const float4 b4 = *reinterpret_cast<const float4*>(&bias[frow0 + tf * 4]);
  const float4 at4 = *reinterpret_cast<const float4*>(
      &att[(fb < 2 ? 0 : 128) + frow0 + tf * 4]);
#pragma unroll
  for (int i = 0; i < 8; ++i) {
    const int nq = (i < 4) ? (tn * 4 + i) : (64 + tn * 4 + (i - 4));
    const int node = n0 + nq;
    float4 r;
    r.x = fmaxf(acc[i][0] + b4.x, 0.0f);
    r.y = fmaxf(acc[i][1] + b4.y, 0.0f);
    r.z = fmaxf(acc[i][2] + b4.z, 0.0f);
    r.w = fmaxf(acc[i][3] + b4.w, 0.0f);
    float pdot = r.x * at4.x + r.y * at4.y + r.z * at4.z + r.w * at4.w;
#pragma unroll
    for (int m2 = 1; m2 < 16; m2 <<= 1) pdot += __shfl_xor(pdot, m2, 16);
    if (node < N) {
      if (fb < 2) {
        *reinterpret_cast<float4*>(&h0[(size_t)node * D + frow0 + tf * 4]) = r;
      } else {
        bf16 p[4] = {__float2bfloat16(r.x), __float2bfloat16(r.y),
                     __float2bfloat16(r.z), __float2bfloat16(r.w)};
        *reinterpret_cast<ushort4*>(&h1b[(size_t)node * D + frow0 + tf * 4]) =
            *reinterpret_cast<const ushort4*>(p);
      }
      if (tf == 0) atomicAdd(&adest[node], pdot);
    }
  }
}

// ---------------------------------------------------------------------------
// Pass A: per-block LDS binning into fixed-capacity bucket regions (64 rows).
// ---------------------------------------------------------------------------
__global__ __launch_bounds__(512) void k_binA(
    const int* __restrict__ row, const int* __restrict__ col,
    int* __restrict__ bukCnt, unsigned* __restrict__ buf1, int E, int NBUK)
{
  constexpr int EPB = 16384;
  __shared__ int hist[1600];
  __shared__ int base[1600];
  const int t = threadIdx.x;
  const int e0 = blockIdx.x * EPB;
  const int e1 = min(e0 + EPB, E);

  for (int i = t; i < NBUK; i += 512) hist[i] = 0;
  __syncthreads();
  for (int e = e0 + t; e < e1; e += 512)
    atomicAdd(&hist[row[e] >> BUCKET_SHIFT], 1);
  __syncthreads();
  for (int bk = t; bk < NBUK; bk += 512) {
    int c = hist[bk];
    base[bk] = (c > 0) ? atomicAdd(&bukCnt[bk], c) : 0;
  }
  __syncthreads();
  for (int i = t; i < NBUK; i += 512) hist[i] = 0;
  __syncthreads();
  for (int e = e0 + t; e < e1; e += 512) {
    int r = row[e];
    int c = col[e];
    int bk = r >> BUCKET_SHIFT;
    int pos = base[bk] + atomicAdd(&hist[bk], 1);
    if (pos < BUCKET_CAP)   // statistically never taken; OOB guard
      buf1[((size_t)bk << BUCKET_CAP_LOG2) + pos] =
          ((unsigned)c << BUCKET_SHIFT) | (unsigned)(r & 63);
  }
}

// ---------------------------------------------------------------------------
// Fused bin + aggregate + norms (replaces k_scanB, k_fine, k_agg).
// One block per 64-row bucket. Phase 1: bin the bucket's buf1 region by
// (wavegroup, seg, rowloc) DIRECTLY INTO an LDS edge list, weight-fused
// (wg = lrelu(a_self[r]) + lrelu(a_neigh[c])). Phase 2: round-11 proven
// engine — wave w walks its contiguous seg-major LDS range with 16-deep
// batched h1 gathers, register accumulate per row, LDS flush on row change.
// No colS2 / runsT global round-trip; no global compaction (k_scanB gone).
// NOTE: h0 aliases d_out; block reads only its own rows, then overwrites them.
// ---------------------------------------------------------------------------
__global__ __launch_bounds__(256) void k_fuse(
    const float* __restrict__ h0, const bf16* __restrict__ h1b,
    const unsigned* __restrict__ buf1, const int* __restrict__ bukCnt,
    const float* __restrict__ a_self, const float* __restrict__ a_neigh,
    const float* __restrict__ scale0, const float* __restrict__ offset0,
    const float* __restrict__ scale1, const float* __restrict__ offset1,
    float* __restrict__ out, int N)
{
  __shared__ float aggL[64 * 128];          // 32 KB accumulator (stride 128: float2 pattern is 2-way/free)
  __shared__ int2  edgesL[BUCKET_CAP];      // 32 KB binned, weight-fused edges
  __shared__ int   lhist[BINS_PER_BUCKET];  // counts -> start positions (in place)
  __shared__ int   lcur[BINS_PER_BUCKET];
  __shared__ int   sd[256];
  __shared__ float asF[64];
  const int b = blockIdx.x;
  const int t = threadIdx.x;
  const int w = t >> 6, l = t & 63;
  const int rbase = b << 6;

  const int n = min(bukCnt[b], BUCKET_CAP);
  const unsigned* src = buf1 + ((size_t)b << BUCKET_CAP_LOG2);

  for (int i = t; i < 64 * 128; i += 256) aggL[i] = 0.f;
  for (int i = t; i < BINS_PER_BUCKET; i += 256) { lhist[i] = 0; lcur[i] = 0; }
  if (t < 64) {
    float v = (rbase + t < N) ? a_self[rbase + t] : 0.f;
    asF[t] = v > 0.f ? v : 0.2f * v;
  }
  __syncthreads();

  // ---- Phase 1a: histogram by (group, seg, rowloc) ----
  for (int i = t; i < n; i += 256) {
    unsigned e = src[i];
    int r = e & 63, c = e >> BUCKET_SHIFT;
    int bin = (((r >> 4) * NSEG) + (c >> SEG_SHIFT)) * 16 + (r & 15);
    atomicAdd(&lhist[bin], 1);
  }
  __syncthreads();
  // ---- Phase 1b: exclusive scan (4 bins/thread), starts in-place ----
  int v4[4], s = 0;
  const int bin0 = t * 4;
#pragma unroll
  for (int i = 0; i < 4; ++i) {
    v4[i] = (bin0 + i < BINS_PER_BUCKET) ? lhist[bin0 + i] : 0;
    s += v4[i];
  }
  sd[t] = s;
  __syncthreads();
  for (int d2 = 1; d2 < 256; d2 <<= 1) {
    int o = (t >= d2) ? sd[t - d2] : 0;
    __syncthreads();
    sd[t] += o;
    __syncthreads();
  }
  int excl = sd[t] - s;
#pragma unroll
  for (int i = 0; i < 4; ++i) {
    if (bin0 + i < BINS_PER_BUCKET) lhist[bin0 + i] = excl;
    excl += v4[i];
  }
  __syncthreads();
  // ---- Phase 1c: scatter into LDS edge list, weight fused ----
  for (int i = t; i < n; i += 256) {
    unsigned e = src[i];
    int r = e & 63, c = e >> BUCKET_SHIFT;
    int bin = (((r >> 4) * NSEG) + (c >> SEG_SHIFT)) * 16 + (r & 15);
    int pos = lhist[bin] + atomicAdd(&lcur[bin], 1);
    float an = a_neigh[c];
    an = an > 0.f ? an : 0.2f * an;
    edgesL[pos] = make_int2((int)(((unsigned)c << 8) | (unsigned)r),
                            __float_as_int(asF[r] + an));
  }
  __syncthreads();

  // ---- Phase 2: aggregate (round-11 engine, straight from LDS) ----
  const char* __restrict__ h1c = reinterpret_cast<const char*>(h1b) + l * 4;
  float acc0 = 0.f, acc1 = 0.f;
  int curRow = -1;

  auto flush = [&]() {
    float* pp = &aggL[(curRow << 7) + 2 * l];
    const float2 o = *reinterpret_cast<const float2*>(pp);
    *reinterpret_cast<float2*>(pp) = make_float2(o.x + acc0, o.y + acc1);
  };
  auto proc = [&](int2 q, unsigned u) {
    const int r_ = q.x & 63;
    if (r_ != curRow) {
      if (curRow >= 0) flush();
      acc0 = 0.f; acc1 = 0.f; curRow = r_;
    }
    const float wg = __int_as_float(q.y);
    acc0 = fmaf(wg, __uint_as_float(u << 16), acc0);
    acc1 = fmaf(wg, __uint_as_float(u & 0xffff0000u), acc1);
  };
  auto ld = [&](int2 q) -> unsigned {
    return *reinterpret_cast<const unsigned*>(
        h1c + (size_t)((unsigned)q.x & 0xFFFFFF00u));
  };

  const int wbeg = lhist[w * BINS_PER_WAVE];
  const int wend = (w < 3) ? lhist[(w + 1) * BINS_PER_WAVE] : n;

  int k = wbeg;
  for (; k + 16 <= wend; k += 16) {
    int2 q[16]; unsigned u[16];
#pragma unroll
    for (int i = 0; i < 16; ++i) q[i] = edgesL[k + i];
#pragma unroll
    for (int i = 0; i < 16; ++i) u[i] = ld(q[i]);
#pragma unroll
    for (int i = 0; i < 16; ++i) proc(q[i], u[i]);
  }
  for (; k + 4 <= wend; k += 4) {
    const int2 q0 = edgesL[k], q1 = edgesL[k + 1], q2 = edgesL[k + 2], q3 = edgesL[k + 3];
    const unsigned u0 = ld(q0), u1 = ld(q1), u2 = ld(q2), u3 = ld(q3);
    proc(q0, u0); proc(q1, u1); proc(q2, u2); proc(q3, u3);
  }
  for (; k < wend; ++k) {
    const int2 q = edgesL[k];
    proc(q, ld(q));
  }
  if (curRow >= 0) flush();
  __syncthreads();

  // ---- Epilogue: both norms + final add ----
  const float2 sc0 = *reinterpret_cast<const float2*>(&scale0[2 * l]);
  const float2 of0 = *reinterpret_cast<const float2*>(&offset0[2 * l]);
  const float2 sc1 = *reinterpret_cast<const float2*>(&scale1[2 * l]);
  const float2 of1 = *reinterpret_cast<const float2*>(&offset1[2 * l]);
  const float inv = 1.0f / 128.0f;
  for (int i = 0; i < 16; ++i) {
    const int rl = (w << 4) + i;
    const int node = rbase + rl;
    if (node >= N) break;
    const float2 hv = *reinterpret_cast<const float2*>(&h0[(size_t)node * D + 2 * l]);
    const float2 av = *reinterpret_cast<const float2*>(&aggL[(rl << 7) + 2 * l]);
    float sh = hv.x + hv.y, qh = hv.x * hv.x + hv.y * hv.y;
    float sa = av.x + av.y, qa = av.x * av.x + av.y * av.y;
#pragma unroll
    for (int o = 32; o; o >>= 1) {
      sh += __shfl_xor(sh, o, 64); qh += __shfl_xor(qh, o, 64);
      sa += __shfl_xor(sa, o, 64); qa += __shfl_xor(qa, o, 64);
    }
    const float m0 = sh * inv, v0 = qh * inv - m0 * m0 + 1e-9f;
    const float m1 = sa * inv, v1 = qa * inv - m1 * m1 + 1e-9f;
    const float r0 = rsqrtf(v0), r1 = rsqrtf(v1);
    float2 o2;
    o2.x = (hv.x - m0) * sc0.x * r0 + of0.x + (av.x - m1) * sc1.x * r1 + of1.x;
    o2.y = (hv.y - m0) * sc0.y * r0 + of0.y + (av.y - m1) * sc1.y * r1 + of1.y;
    *reinterpret_cast<float2*>(&out[(size_t)node * D + 2 * l]) = o2;
  }
}

// ---------------------------------------------------------------------------
extern "C" void kernel_launch(void* const* d_in, const int* in_sizes, int n_in,
                              void* d_out, int out_size, void* d_ws, size_t ws_size,
                              hipStream_t stream)
{
  const float* x       = (const float*)d_in[0];
  const int*   row     = (const int*)d_in[1];
  const int*   col     = (const int*)d_in[2];
  const float* W0      = (const float*)d_in[3];
  const float* b0      = (const float*)d_in[4];
  const float* W1      = (const float*)d_in[5];
  const float* b1      = (const float*)d_in[6];
  const float* att     = (const float*)d_in[7];
  const float* scale0  = (const float*)d_in[8];
  const float* offset0 = (const float*)d_in[9];
  const float* scale1  = (const float*)d_in[10];
  const float* offset1 = (const float*)d_in[11];

  const int N = in_sizes[0] / D;
  const int E = in_sizes[1];
  const int NBUK = (N + 63) >> BUCKET_SHIFT;

  char* ws = (char*)d_ws;
  size_t off = 0;
  auto alloc = [&](size_t bytes) -> void* {
    void* p = ws + off;
    off += (bytes + 511) & ~size_t(511);
    return p;
  };

  float*    h0      = (float*)d_out;                 // alias into d_out
  bf16*     h1b     = (bf16*)alloc((size_t)N * D * sizeof(bf16));
  float*    a_self  = (float*)alloc((size_t)N * sizeof(float));
  float*    a_neigh = (float*)alloc((size_t)N * sizeof(float));
  int*      bukCnt  = (int*)alloc((size_t)NBUK * sizeof(int));
  unsigned* buf1    = (unsigned*)alloc(((size_t)NBUK << BUCKET_CAP_LOG2) * sizeof(unsigned));

  hipMemsetAsync(a_self, 0, (size_t)N * sizeof(float), stream);
  hipMemsetAsync(a_neigh, 0, (size_t)N * sizeof(float), stream);
  hipMemsetAsync(bukCnt, 0, (size_t)NBUK * sizeof(int), stream);

  dim3 ggrid((N + 127) / 128, 4);
  k_gemm<<<ggrid, 256, 0, stream>>>(x, W0, b0, W1, b1, att, h0, h1b,
                                    a_self, a_neigh, N);
  const int NBLKA = (E + 16383) / 16384;
  k_binA<<<NBLKA, 512, 0, stream>>>(row, col, bukCnt, buf1, E, NBUK);
  k_fuse<<<NBUK, 256, 0, stream>>>(h0, h1b, buf1, bukCnt, a_self, a_neigh,
                                   scale0, offset0, scale1, offset1,
                                   (float*)d_out, N);
}

// Round 14
// 292.086 us; speedup vs baseline: 1.3339x; 1.3339x over previous
//
#include <hip/hip_runtime.h>
#include <hip/hip_bf16.h>

constexpr int D = 128;
constexpr int BUCKET_SHIFT = 6;        // 64 rows per bucket (= k_agg block)
constexpr int BUCKET_CAP_LOG2 = 12;    // 4096 slots per bucket (mean 2048)
constexpr int BUCKET_CAP = 1 << BUCKET_CAP_LOG2;
constexpr int SEG_SHIFT = 13;          // 8192 source rows per segment = 2MB bf16
constexpr int NSEG = 13;               // ceil(100000 / 8192)
constexpr int BINS_PER_BUCKET = 4 * NSEG * 16;   // (group, seg, rowloc) = 832
constexpr int BINS_PER_WAVE = NSEG * 16;         // 208
constexpr int ROWSTRIDE = 130;         // f32 LDS row stride
typedef __hip_bfloat16 bf16;
typedef __attribute__((ext_vector_type(8))) short bf16x8;
typedef __attribute__((ext_vector_type(4))) float f32x4;

__device__ __forceinline__ short f2b(float f) {
  bf16 h = __float2bfloat16(f);
  return *reinterpret_cast<short*>(&h);
}

// ---------------------------------------------------------------------------
// W f32 -> bf16 pre-conversion (64 KB total, one-shot).
// ---------------------------------------------------------------------------
__global__ void k_cvtW(const float* __restrict__ W0, const float* __restrict__ W1,
                       short* __restrict__ Wb0, short* __restrict__ Wb1)
{
  int i = blockIdx.x * 256 + threadIdx.x;
  if (i < 16384) Wb0[i] = f2b(W0[i]);
  else if (i < 32768) { int j = i - 16384; Wb1[j] = f2b(W1[j]); }
}

// ---------------------------------------------------------------------------
// MFMA GEMM + exact in-wave attention dots.
//   fb=0: h0 = relu(x W0^T + b0) [f32], a_self[n] = h0[n].att[:128] (raw)
//   fb=1: h1 = relu(x W1^T + b1) [bf16], a_neigh[n] = h1[n].att[128:] (raw)
// Block = 256 th = 4 waves; wave owns 16 nodes, full feat dim via 8 N-tiles
// x 4 K-steps of mfma_f32_16x16x32_bf16. A-frag: row=lane&15, K-grp=lane>>4
// (8 contiguous k). B-frag: col=lane&15 (W row), same K packing -> 16B loads
// from bf16 W (L2-resident). C/D: col=lane&15, row=(lane>>4)*4+reg [m89].
// Attention dot completes in-wave (16-lane shuffle) -> direct store, no atomic.
// ---------------------------------------------------------------------------
__global__ __launch_bounds__(256) void k_gemm(
    const float* __restrict__ x,
    const short* __restrict__ Wb0, const float* __restrict__ b0,
    const short* __restrict__ Wb1, const float* __restrict__ b1,
    const float* __restrict__ att,
    float* __restrict__ h0, bf16* __restrict__ h1b,
    float* __restrict__ a_self, float* __restrict__ a_neigh, int N)
{
  const int t = threadIdx.x;
  const int wv = t >> 6;
  const int l = t & 63;
  const int fb = blockIdx.y;
  const int nbase = blockIdx.x * 64 + wv * 16;
  const int lm = l & 15;      // A row / C-D col
  const int lk = l >> 4;      // K group (8 elems)

  const short* __restrict__ W    = fb ? Wb1 : Wb0;
  const float* __restrict__ bias = fb ? b1 : b0;
  const float* __restrict__ attp = att + fb * 128;

  f32x4 acc[8];
#pragma unroll
  for (int i = 0; i < 8; ++i) acc[i] = (f32x4){0.f, 0.f, 0.f, 0.f};

  const int node_a = nbase + lm;
  const bool okA = node_a < N;
  const float* xrow = x + (size_t)node_a * D + lk * 8;

#pragma unroll
  for (int ks = 0; ks < 4; ++ks) {
    float4 a0, a1;
    if (okA) {
      a0 = *reinterpret_cast<const float4*>(xrow + ks * 32);
      a1 = *reinterpret_cast<const float4*>(xrow + ks * 32 + 4);
    } else {
      a0 = make_float4(0.f, 0.f, 0.f, 0.f);
      a1 = a0;
    }
    bf16x8 af;
    af[0] = f2b(a0.x); af[1] = f2b(a0.y); af[2] = f2b(a0.z); af[3] = f2b(a0.w);
    af[4] = f2b(a1.x); af[5] = f2b(a1.y); af[6] = f2b(a1.z); af[7] = f2b(a1.w);
#pragma unroll
    for (int nt = 0; nt < 8; ++nt) {
      const bf16x8 bfr = *reinterpret_cast<const bf16x8*>(
          W + (size_t)(nt * 16 + lm) * D + ks * 32 + lk * 8);
      acc[nt] = __builtin_amdgcn_mfma_f32_16x16x32_bf16(af, bfr, acc[nt], 0, 0, 0);
    }
  }

  float pd[4] = {0.f, 0.f, 0.f, 0.f};
#pragma unroll
  for (int nt = 0; nt < 8; ++nt) {
    const int f = nt * 16 + lm;
    const float bv = bias[f];
    const float av = attp[f];
#pragma unroll
    for (int j = 0; j < 4; ++j) {
      const float r = fmaxf(acc[nt][j] + bv, 0.f);
      pd[j] = fmaf(r, av, pd[j]);
      const int ng = nbase + lk * 4 + j;
      if (ng < N) {
        if (fb == 0) h0[(size_t)ng * D + f] = r;
        else         h1b[(size_t)ng * D + f] = __float2bfloat16(r);
      }
    }
  }
#pragma unroll
  for (int m2 = 1; m2 < 16; m2 <<= 1) {
    pd[0] += __shfl_xor(pd[0], m2, 16);
    pd[1] += __shfl_xor(pd[1], m2, 16);
    pd[2] += __shfl_xor(pd[2], m2, 16);
    pd[3] += __shfl_xor(pd[3], m2, 16);
  }
  if (lm == 0) {
    float* __restrict__ adest = fb ? a_neigh : a_self;
#pragma unroll
    for (int j = 0; j < 4; ++j) {
      const int ng = nbase + lk * 4 + j;
      if (ng < N) adest[ng] = pd[j];
    }
  }
}

// ---------------------------------------------------------------------------
// Pass A: per-block LDS binning into fixed-capacity bucket regions (64 rows).
// ---------------------------------------------------------------------------
__global__ __launch_bounds__(512) void k_binA(
    const int* __restrict__ row, const int* __restrict__ col,
    int* __restrict__ bukCnt, unsigned* __restrict__ buf1, int E, int NBUK)
{
  constexpr int EPB = 16384;
  __shared__ int hist[1600];
  __shared__ int base[1600];
  const int t = threadIdx.x;
  const int e0 = blockIdx.x * EPB;
  const int e1 = min(e0 + EPB, E);

  for (int i = t; i < NBUK; i += 512) hist[i] = 0;
  __syncthreads();
  for (int e = e0 + t; e < e1; e += 512)
    atomicAdd(&hist[row[e] >> BUCKET_SHIFT], 1);
  __syncthreads();
  for (int bk = t; bk < NBUK; bk += 512) {
    int c = hist[bk];
    base[bk] = (c > 0) ? atomicAdd(&bukCnt[bk], c) : 0;
  }
  __syncthreads();
  for (int i = t; i < NBUK; i += 512) hist[i] = 0;
  __syncthreads();
  for (int e = e0 + t; e < e1; e += 512) {
    int r = row[e];
    int c = col[e];
    int bk = r >> BUCKET_SHIFT;
    int pos = base[bk] + atomicAdd(&hist[bk], 1);
    if (pos < BUCKET_CAP)   // statistically never taken; OOB guard
      buf1[((size_t)bk << BUCKET_CAP_LOG2) + pos] =
          ((unsigned)c << BUCKET_SHIFT) | (unsigned)(r & 63);
  }
}

// exclusive scan of bucket counts + runs sentinel
__global__ __launch_bounds__(1024) void k_scanB(
    const int* __restrict__ bukCnt, int* __restrict__ bukBase,
    int* __restrict__ runs, int NBUK)
{
  __shared__ int sd[1024];
  __shared__ int carry;
  const int t = threadIdx.x;
  if (t == 0) carry = 0;
  __syncthreads();
  for (int r = 0; r * 1024 < NBUK; ++r) {
    const int idx = r * 1024 + t;
    const int v = (idx < NBUK) ? min(bukCnt[idx], BUCKET_CAP) : 0;
    sd[t] = v;
    __syncthreads();
    for (int d2 = 1; d2 < 1024; d2 <<= 1) {
      int o = (t >= d2) ? sd[t - d2] : 0;
      __syncthreads();
      sd[t] += o;
      __syncthreads();
    }
    const int c0 = carry;
    if (idx < NBUK) bukBase[idx] = c0 + sd[t] - v;
    __syncthreads();
    if (t == 1023) carry = c0 + sd[1023];
    __syncthreads();
  }
  if (t == 0) runs[(size_t)NBUK * BINS_PER_BUCKET] = carry;
}

// ---------------------------------------------------------------------------
// Pass B: one block per bucket. Bins edges by (rowgroup, seg, rowloc) so the
// edge array is contiguous, seg-major and row-sorted per wave-group range.
// Precomputes the COMPLETE edge weight wg = lrelu(a_self[r]) +
// lrelu(a_neigh[c]) and emits gather-ready int2 { (col<<8)|rowloc, wg }.
// ---------------------------------------------------------------------------
__global__ __launch_bounds__(256) void k_fine(
    const unsigned* __restrict__ buf1,
    const int* __restrict__ bukCnt, const int* __restrict__ bukBase,
    const float* __restrict__ a_self, const float* __restrict__ a_neigh,
    int* __restrict__ runs, int2* __restrict__ colS2, int N)
{
  __shared__ int lhist[BINS_PER_BUCKET], labs[BINS_PER_BUCKET], lcur[BINS_PER_BUCKET];
  __shared__ float asF[64];
  __shared__ int sd[256];
  const int b = blockIdx.x;
  const int t = threadIdx.x;
  const int n = min(bukCnt[b], BUCKET_CAP);
  const unsigned* src = buf1 + ((size_t)b << BUCKET_CAP_LOG2);
  const int rstart = b << BUCKET_SHIFT;

  for (int i = t; i < BINS_PER_BUCKET; i += 256) { lhist[i] = 0; lcur[i] = 0; }
  if (t < 64) {
    float v = (rstart + t < N) ? a_self[rstart + t] : 0.f;
    asF[t] = v > 0.f ? v : 0.2f * v;
  }
  __syncthreads();
  for (int i = t; i < n; i += 256) {
    unsigned e = src[i];
    int r = e & 63, c = e >> BUCKET_SHIFT;
    int bin = (((r >> 4) * NSEG) + (c >> SEG_SHIFT)) * 16 + (r & 15);
    atomicAdd(&lhist[bin], 1);
  }
  __syncthreads();
  int v[4], s = 0;
  const int bin0 = t * 4;
#pragma unroll
  for (int i = 0; i < 4; ++i) {
    v[i] = (bin0 + i < BINS_PER_BUCKET) ? lhist[bin0 + i] : 0;
    s += v[i];
  }
  sd[t] = s;
  __syncthreads();
  for (int d2 = 1; d2 < 256; d2 <<= 1) {
    int o = (t >= d2) ? sd[t - d2] : 0;
    __syncthreads();
    sd[t] += o;
    __syncthreads();
  }
  int excl = sd[t] - s;
  const int gb = bukBase[b];
#pragma unroll
  for (int i = 0; i < 4; ++i) {
    if (bin0 + i < BINS_PER_BUCKET) {
      labs[bin0 + i] = gb + excl;
      runs[(size_t)b * BINS_PER_BUCKET + bin0 + i] = gb + excl;
    }
    excl += v[i];
  }
  __syncthreads();
  for (int i = t; i < n; i += 256) {
    unsigned e = src[i];
    int r = e & 63, c = e >> BUCKET_SHIFT;
    int bin = (((r >> 4) * NSEG) + (c >> SEG_SHIFT)) * 16 + (r & 15);
    int pos = labs[bin] + atomicAdd(&lcur[bin], 1);
    float an = a_neigh[c];
    an = an > 0.f ? an : 0.2f * an;
    colS2[pos] = make_int2((c << 8) | r, __float_as_int(asF[r] + an));
  }
}

// ---------------------------------------------------------------------------
// Segment-swept aggregate (round-11/12 proven engine).
// Block = 64 nodes, 4 waves; wave w owns rows w*16..w*16+15 and one
// CONTIGUOUS seg-major edge range; 16-deep batched h1 gathers; register
// accumulate per row, LDS flush on row change.
// NOTE: h0 aliases d_out; block reads only its own rows, then overwrites them.
// ---------------------------------------------------------------------------
__global__ __launch_bounds__(256) void k_agg(
    const float* __restrict__ h0, const bf16* __restrict__ h1b,
    const int* __restrict__ runs, const int2* __restrict__ colS2,
    const float* __restrict__ scale0, const float* __restrict__ offset0,
    const float* __restrict__ scale1, const float* __restrict__ offset1,
    float* __restrict__ out, int N)
{
  __shared__ float aggL[64 * ROWSTRIDE];          // 33.3 KB accumulator
  __shared__ int wb[5];                           // wave range boundaries
  __shared__ int2 je[4][64];                      // wave-private staging
  const int b = blockIdx.x;
  const int t = threadIdx.x;
  const int w = t >> 6, l = t & 63;
  const int rbase = b << 6;

  for (int i = t; i < 64 * ROWSTRIDE; i += 256) aggL[i] = 0.f;
  if (t < 5) wb[t] = runs[(size_t)b * BINS_PER_BUCKET + (size_t)t * BINS_PER_WAVE];
  __syncthreads();

  const char* h1c = reinterpret_cast<const char*>(h1b) + l * 4;
  int2* jw = je[w];
  float acc0 = 0.f, acc1 = 0.f;
  int curRow = -1;

  auto flush = [&]() {
    float* pp = &aggL[curRow * ROWSTRIDE + 2 * l];
    const float2 o = *reinterpret_cast<const float2*>(pp);
    *reinterpret_cast<float2*>(pp) = make_float2(o.x + acc0, o.y + acc1);
  };
  auto proc = [&](int2 q, unsigned u) {
    const int r_ = q.x & 63;
    if (r_ != curRow) {
      if (curRow >= 0) flush();
      acc0 = 0.f; acc1 = 0.f; curRow = r_;
    }
    const float wg = __int_as_float(q.y);
    acc0 = fmaf(wg, __uint_as_float(u << 16), acc0);
    acc1 = fmaf(wg, __uint_as_float(u & 0xffff0000u), acc1);
  };
  auto ld = [&](int2 q) -> unsigned {
    return *reinterpret_cast<const unsigned*>(
        h1c + (size_t)((unsigned)q.x & 0xFFFFFF00u));
  };

  const int wbeg = wb[w];
  const int wend = wb[w + 1];

  if (wbeg < wend) {
    const int last = wend - 1;
    int2 P = colS2[min(wbeg + l, last)];   // chunk 0 in hand

    int cur = wbeg;
    while (cur < wend) {
      const int m = min(64, wend - cur);
      if (l < m) jw[l] = P;
      const int2 Pn = colS2[min(cur + 64 + l, last)];   // prefetch next chunk

      int k = 0;
      for (; k + 16 <= m; k += 16) {
        int2 q[16]; unsigned u[16];
#pragma unroll
        for (int i = 0; i < 16; ++i) q[i] = jw[k + i];
#pragma unroll
        for (int i = 0; i < 16; ++i) u[i] = ld(q[i]);
#pragma unroll
        for (int i = 0; i < 16; ++i) proc(q[i], u[i]);
      }
      for (; k + 4 <= m; k += 4) {
        const int2 q0 = jw[k], q1 = jw[k + 1], q2 = jw[k + 2], q3 = jw[k + 3];
        const unsigned u0 = ld(q0), u1 = ld(q1), u2 = ld(q2), u3 = ld(q3);
        proc(q0, u0); proc(q1, u1); proc(q2, u2); proc(q3, u3);
      }
      for (; k < m; ++k) {
        const int2 q = jw[k];
        proc(q, ld(q));
      }
      P = Pn;
      cur += m;
    }
    if (curRow >= 0) flush();
  }
  __syncthreads();

  const float2 sc0 = *reinterpret_cast<const float2*>(&scale0[2 * l]);
  const float2 of0 = *reinterpret_cast<const float2*>(&offset0[2 * l]);
  const float2 sc1 = *reinterpret_cast<const float2*>(&scale1[2 * l]);
  const float2 of1 = *reinterpret_cast<const float2*>(&offset1[2 * l]);
  const float inv = 1.0f / 128.0f;
  for (int i = 0; i < 16; ++i) {
    const int node = rbase + (w << 4) + i;
    if (node >= N) break;
    const float2 hv = *reinterpret_cast<const float2*>(&h0[(size_t)node * D + 2 * l]);
    const float2 av = *reinterpret_cast<const float2*>(
        &aggL[((w << 4) + i) * ROWSTRIDE + 2 * l]);
    float sh = hv.x + hv.y, qh = hv.x * hv.x + hv.y * hv.y;
    float sa = av.x + av.y, qa = av.x * av.x + av.y * av.y;
#pragma unroll
    for (int o = 32; o; o >>= 1) {
      sh += __shfl_xor(sh, o, 64); qh += __shfl_xor(qh, o, 64);
      sa += __shfl_xor(sa, o, 64); qa += __shfl_xor(qa, o, 64);
    }
    const float m0 = sh * inv, v0 = qh * inv - m0 * m0 + 1e-9f;
    const float m1 = sa * inv, v1 = qa * inv - m1 * m1 + 1e-9f;
    const float r0 = rsqrtf(v0), r1 = rsqrtf(v1);
    float2 o2;
    o2.x = (hv.x - m0) * sc0.x * r0 + of0.x + (av.x - m1) * sc1.x * r1 + of1.x;
    o2.y = (hv.y - m0) * sc0.y * r0 + of0.y + (av.y - m1) * sc1.y * r1 + of1.y;
    *reinterpret_cast<float2*>(&out[(size_t)node * D + 2 * l]) = o2;
  }
}

// ---------------------------------------------------------------------------
extern "C" void kernel_launch(void* const* d_in, const int* in_sizes, int n_in,
                              void* d_out, int out_size, void* d_ws, size_t ws_size,
                              hipStream_t stream)
{
  const float* x       = (const float*)d_in[0];
  const int*   row     = (const int*)d_in[1];
  const int*   col     = (const int*)d_in[2];
  const float* W0      = (const float*)d_in[3];
  const float* b0      = (const float*)d_in[4];
  const float* W1      = (const float*)d_in[5];
  const float* b1      = (const float*)d_in[6];
  const float* att     = (const float*)d_in[7];
  const float* scale0  = (const float*)d_in[8];
  const float* offset0 = (const float*)d_in[9];
  const float* scale1  = (const float*)d_in[10];
  const float* offset1 = (const float*)d_in[11];

  const int N = in_sizes[0] / D;
  const int E = in_sizes[1];
  const int NBUK = (N + 63) >> BUCKET_SHIFT;

  char* ws = (char*)d_ws;
  size_t off = 0;
  auto alloc = [&](size_t bytes) -> void* {
    void* p = ws + off;
    off += (bytes + 511) & ~size_t(511);
    return p;
  };

  float*    h0      = (float*)d_out;                 // alias into d_out
  bf16*     h1b     = (bf16*)alloc((size_t)N * D * sizeof(bf16));
  float*    a_self  = (float*)alloc((size_t)N * sizeof(float));
  float*    a_neigh = (float*)alloc((size_t)N * sizeof(float));
  short*    Wb0     = (short*)alloc(16384 * sizeof(short));
  short*    Wb1     = (short*)alloc(16384 * sizeof(short));
  int*      bukCnt  = (int*)alloc((size_t)NBUK * sizeof(int));
  int*      bukBase = (int*)alloc((size_t)NBUK * sizeof(int));
  int*      runsT   = (int*)alloc(((size_t)NBUK * BINS_PER_BUCKET + 1) * sizeof(int));
  unsigned* buf1    = (unsigned*)alloc(((size_t)NBUK << BUCKET_CAP_LOG2) * sizeof(unsigned));
  int2*     colS2   = (int2*)alloc((size_t)E * sizeof(int2));

  hipMemsetAsync(bukCnt, 0, (size_t)NBUK * sizeof(int), stream);

  k_cvtW<<<128, 256, 0, stream>>>(W0, W1, Wb0, Wb1);
  dim3 ggrid((N + 63) / 64, 2);
  k_gemm<<<ggrid, 256, 0, stream>>>(x, Wb0, b0, Wb1, b1, att, h0, h1b,
                                    a_self, a_neigh, N);
  const int NBLKA = (E + 16383) / 16384;
  k_binA<<<NBLKA, 512, 0, stream>>>(row, col, bukCnt, buf1, E, NBUK);
  k_scanB<<<1, 1024, 0, stream>>>(bukCnt, bukBase, runsT, NBUK);
  k_fine<<<NBUK, 256, 0, stream>>>(buf1, bukCnt, bukBase, a_self, a_neigh,
                                   runsT, colS2, N);
  k_agg<<<NBUK, 256, 0, stream>>>(h0, h1b, runsT, colS2,
                                  scale0, offset0, scale1, offset1,
                                  (float*)d_out, N);
}

// Round 15
// 285.606 us; speedup vs baseline: 1.3641x; 1.0227x over previous
//
#include <hip/hip_runtime.h>
#include <hip/hip_bf16.h>

constexpr int D = 128;
constexpr int BUCKET_SHIFT = 6;        // 64 rows per bucket (= k_agg block)
constexpr int BUCKET_CAP_LOG2 = 12;    // 4096 slots per bucket (mean 2048)
constexpr int BUCKET_CAP = 1 << BUCKET_CAP_LOG2;
constexpr int SEG_SHIFT = 13;          // 8192 source rows per segment = 2MB bf16
constexpr int NSEG = 13;               // ceil(100000 / 8192)
constexpr int BINS_PER_BUCKET = 4 * NSEG * 16;   // (group, seg, rowloc) = 832
constexpr int BINS_PER_WAVE = NSEG * 16;         // 208
constexpr int ROWSTRIDE = 130;         // f32 LDS row stride
typedef __hip_bfloat16 bf16;
typedef __attribute__((ext_vector_type(8))) short bf16x8;
typedef __attribute__((ext_vector_type(4))) float f32x4;

__device__ __forceinline__ short f2b(float f) {
  bf16 h = __float2bfloat16(f);
  return *reinterpret_cast<short*>(&h);
}

// ---------------------------------------------------------------------------
// W f32 -> bf16 pre-conversion (64 KB total, one-shot).
// ---------------------------------------------------------------------------
__global__ void k_cvtW(const float* __restrict__ W0, const float* __restrict__ W1,
                       short* __restrict__ Wb0, short* __restrict__ Wb1)
{
  int i = blockIdx.x * 256 + threadIdx.x;
  if (i < 16384) Wb0[i] = f2b(W0[i]);
  else if (i < 32768) { int j = i - 16384; Wb1[j] = f2b(W1[j]); }
}

// ---------------------------------------------------------------------------
// MFMA GEMM + exact in-wave attention dots (proven round 14).
// ---------------------------------------------------------------------------
__global__ __launch_bounds__(256) void k_gemm(
    const float* __restrict__ x,
    const short* __restrict__ Wb0, const float* __restrict__ b0,
    const short* __restrict__ Wb1, const float* __restrict__ b1,
    const float* __restrict__ att,
    float* __restrict__ h0, bf16* __restrict__ h1b,
    float* __restrict__ a_self, float* __restrict__ a_neigh, int N)
{
  const int t = threadIdx.x;
  const int wv = t >> 6;
  const int l = t & 63;
  const int fb = blockIdx.y;
  const int nbase = blockIdx.x * 64 + wv * 16;
  const int lm = l & 15;      // A row / C-D col
  const int lk = l >> 4;      // K group (8 elems)

  const short* __restrict__ W    = fb ? Wb1 : Wb0;
  const float* __restrict__ bias = fb ? b1 : b0;
  const float* __restrict__ attp = att + fb * 128;

  f32x4 acc[8];
#pragma unroll
  for (int i = 0; i < 8; ++i) acc[i] = (f32x4){0.f, 0.f, 0.f, 0.f};

  const int node_a = nbase + lm;
  const bool okA = node_a < N;
  const float* xrow = x + (size_t)node_a * D + lk * 8;

#pragma unroll
  for (int ks = 0; ks < 4; ++ks) {
    float4 a0, a1;
    if (okA) {
      a0 = *reinterpret_cast<const float4*>(xrow + ks * 32);
      a1 = *reinterpret_cast<const float4*>(xrow + ks * 32 + 4);
    } else {
      a0 = make_float4(0.f, 0.f, 0.f, 0.f);
      a1 = a0;
    }
    bf16x8 af;
    af[0] = f2b(a0.x); af[1] = f2b(a0.y); af[2] = f2b(a0.z); af[3] = f2b(a0.w);
    af[4] = f2b(a1.x); af[5] = f2b(a1.y); af[6] = f2b(a1.z); af[7] = f2b(a1.w);
#pragma unroll
    for (int nt = 0; nt < 8; ++nt) {
      const bf16x8 bfr = *reinterpret_cast<const bf16x8*>(
          W + (size_t)(nt * 16 + lm) * D + ks * 32 + lk * 8);
      acc[nt] = __builtin_amdgcn_mfma_f32_16x16x32_bf16(af, bfr, acc[nt], 0, 0, 0);
    }
  }

  float pd[4] = {0.f, 0.f, 0.f, 0.f};
#pragma unroll
  for (int nt = 0; nt < 8; ++nt) {
    const int f = nt * 16 + lm;
    const float bv = bias[f];
    const float av = attp[f];
#pragma unroll
    for (int j = 0; j < 4; ++j) {
      const float r = fmaxf(acc[nt][j] + bv, 0.f);
      pd[j] = fmaf(r, av, pd[j]);
      const int ng = nbase + lk * 4 + j;
      if (ng < N) {
        if (fb == 0) h0[(size_t)ng * D + f] = r;
        else         h1b[(size_t)ng * D + f] = __float2bfloat16(r);
      }
    }
  }
#pragma unroll
  for (int m2 = 1; m2 < 16; m2 <<= 1) {
    pd[0] += __shfl_xor(pd[0], m2, 16);
    pd[1] += __shfl_xor(pd[1], m2, 16);
    pd[2] += __shfl_xor(pd[2], m2, 16);
    pd[3] += __shfl_xor(pd[3], m2, 16);
  }
  if (lm == 0) {
    float* __restrict__ adest = fb ? a_neigh : a_self;
#pragma unroll
    for (int j = 0; j < 4; ++j) {
      const int ng = nbase + lk * 4 + j;
      if (ng < N) adest[ng] = pd[j];
    }
  }
}

// ---------------------------------------------------------------------------
// Pass A: per-block LDS binning into fixed-capacity bucket regions (64 rows).
// ---------------------------------------------------------------------------
__global__ __launch_bounds__(512) void k_binA(
    const int* __restrict__ row, const int* __restrict__ col,
    int* __restrict__ bukCnt, unsigned* __restrict__ buf1, int E, int NBUK)
{
  constexpr int EPB = 16384;
  __shared__ int hist[1600];
  __shared__ int base[1600];
  const int t = threadIdx.x;
  const int e0 = blockIdx.x * EPB;
  const int e1 = min(e0 + EPB, E);

  for (int i = t; i < NBUK; i += 512) hist[i] = 0;
  __syncthreads();
  for (int e = e0 + t; e < e1; e += 512)
    atomicAdd(&hist[row[e] >> BUCKET_SHIFT], 1);
  __syncthreads();
  for (int bk = t; bk < NBUK; bk += 512) {
    int c = hist[bk];
    base[bk] = (c > 0) ? atomicAdd(&bukCnt[bk], c) : 0;
  }
  __syncthreads();
  for (int i = t; i < NBUK; i += 512) hist[i] = 0;
  __syncthreads();
  for (int e = e0 + t; e < e1; e += 512) {
    int r = row[e];
    int c = col[e];
    int bk = r >> BUCKET_SHIFT;
    int pos = base[bk] + atomicAdd(&hist[bk], 1);
    if (pos < BUCKET_CAP)   // statistically never taken; OOB guard
      buf1[((size_t)bk << BUCKET_CAP_LOG2) + pos] =
          ((unsigned)c << BUCKET_SHIFT) | (unsigned)(r & 63);
  }
}

// ---------------------------------------------------------------------------
// Pass B: one block per bucket. Bins edges by (rowgroup, seg, rowloc) so the
// edge array is contiguous, seg-major and row-sorted per wave-group range.
// Emits gather-ready int2 { (col<<8)|rowloc, wg } with the COMPLETE edge
// weight wg = lrelu(a_self[r]) + lrelu(a_neigh[c]) fused.
// NEW: self-computes its global compaction base (sum of bukCnt[0..b), L2-hot)
// — k_scanB eliminated; writes only the 5 wave boundaries per bucket.
// ---------------------------------------------------------------------------
__global__ __launch_bounds__(256) void k_fine(
    const unsigned* __restrict__ buf1,
    const int* __restrict__ bukCnt,
    const float* __restrict__ a_self, const float* __restrict__ a_neigh,
    int* __restrict__ runsW, int2* __restrict__ colS2, int N)
{
  __shared__ int lhist[BINS_PER_BUCKET], labs[BINS_PER_BUCKET], lcur[BINS_PER_BUCKET];
  __shared__ float asF[64];
  __shared__ int sd[256];
  __shared__ int gbS;
  const int b = blockIdx.x;
  const int t = threadIdx.x;
  const int n = min(bukCnt[b], BUCKET_CAP);
  const unsigned* src = buf1 + ((size_t)b << BUCKET_CAP_LOG2);
  const int rstart = b << BUCKET_SHIFT;

  // ---- self-computed compaction base gb = sum_{i<b} min(bukCnt[i],CAP) ----
  int pre = 0;
  for (int i = t; i < b; i += 256) pre += min(bukCnt[i], BUCKET_CAP);
  sd[t] = pre;
  __syncthreads();
  for (int d2 = 128; d2 > 0; d2 >>= 1) {
    if (t < d2) sd[t] += sd[t + d2];
    __syncthreads();
  }
  if (t == 0) gbS = sd[0];

  for (int i = t; i < BINS_PER_BUCKET; i += 256) { lhist[i] = 0; lcur[i] = 0; }
  if (t < 64) {
    float v = (rstart + t < N) ? a_self[rstart + t] : 0.f;
    asF[t] = v > 0.f ? v : 0.2f * v;
  }
  __syncthreads();
  const int gb = gbS;

  // histogram by (group, seg, rowloc)
  for (int i = t; i < n; i += 256) {
    unsigned e = src[i];
    int r = e & 63, c = e >> BUCKET_SHIFT;
    int bin = (((r >> 4) * NSEG) + (c >> SEG_SHIFT)) * 16 + (r & 15);
    atomicAdd(&lhist[bin], 1);
  }
  __syncthreads();
  // exclusive scan (4 bins/thread)
  int v[4], s = 0;
  const int bin0 = t * 4;
#pragma unroll
  for (int i = 0; i < 4; ++i) {
    v[i] = (bin0 + i < BINS_PER_BUCKET) ? lhist[bin0 + i] : 0;
    s += v[i];
  }
  sd[t] = s;
  __syncthreads();
  for (int d2 = 1; d2 < 256; d2 <<= 1) {
    int o = (t >= d2) ? sd[t - d2] : 0;
    __syncthreads();
    sd[t] += o;
    __syncthreads();
  }
  int excl = sd[t] - s;
#pragma unroll
  for (int i = 0; i < 4; ++i) {
    if (bin0 + i < BINS_PER_BUCKET) labs[bin0 + i] = gb + excl;
    excl += v[i];
  }
  __syncthreads();
  // wave boundaries only (k_agg reads exactly these 5)
  if (t < 4) runsW[b * 5 + t] = labs[t * BINS_PER_WAVE];
  else if (t == 4) runsW[b * 5 + 4] = gb + n;
  // scatter, weight-fused
  for (int i = t; i < n; i += 256) {
    unsigned e = src[i];
    int r = e & 63, c = e >> BUCKET_SHIFT;
    int bin = (((r >> 4) * NSEG) + (c >> SEG_SHIFT)) * 16 + (r & 15);
    int pos = labs[bin] + atomicAdd(&lcur[bin], 1);
    float an = a_neigh[c];
    an = an > 0.f ? an : 0.2f * an;
    colS2[pos] = make_int2((c << 8) | r, __float_as_int(asF[r] + an));
  }
}

// ---------------------------------------------------------------------------
// Segment-swept aggregate, stageless. Block = 64 nodes, 4 waves; wave w owns
// rows w*16..w*16+15 and one CONTIGUOUS seg-major edge range.
// NEW: edge entries are read DIRECTLY from global at wave-uniform indices
// (readfirstlane-forced) — no LDS staging, no ds_write/ds_read per edge, no
// prefetch bookkeeping. 16-deep batched h1 gathers; register accumulate per
// row (row-sorted), LDS flush on row change.
// NOTE: h0 aliases d_out; block reads only its own rows, then overwrites them.
// ---------------------------------------------------------------------------
__global__ __launch_bounds__(256) void k_agg(
    const float* __restrict__ h0, const bf16* __restrict__ h1b,
    const int* __restrict__ runsW, const int2* __restrict__ colS2,
    const float* __restrict__ scale0, const float* __restrict__ offset0,
    const float* __restrict__ scale1, const float* __restrict__ offset1,
    float* __restrict__ out, int N)
{
  __shared__ float aggL[64 * ROWSTRIDE];          // 33.3 KB accumulator
  __shared__ int wb[5];                           // wave range boundaries
  const int b = blockIdx.x;
  const int t = threadIdx.x;
  const int w = t >> 6, l = t & 63;
  const int rbase = b << 6;

  for (int i = t; i < 64 * ROWSTRIDE; i += 256) aggL[i] = 0.f;
  if (t < 5) wb[t] = runsW[b * 5 + t];
  __syncthreads();

  const char* h1c = reinterpret_cast<const char*>(h1b) + l * 4;
  float acc0 = 0.f, acc1 = 0.f;
  int curRow = -1;

  auto flush = [&]() {
    float* pp = &aggL[curRow * ROWSTRIDE + 2 * l];
    const float2 o = *reinterpret_cast<const float2*>(pp);
    *reinterpret_cast<float2*>(pp) = make_float2(o.x + acc0, o.y + acc1);
  };
  auto proc = [&](int2 q, unsigned u) {
    const int r_ = q.x & 63;
    if (r_ != curRow) {
      if (curRow >= 0) flush();
      acc0 = 0.f; acc1 = 0.f; curRow = r_;
    }
    const float wg = __int_as_float(q.y);
    acc0 = fmaf(wg, __uint_as_float(u << 16), acc0);
    acc1 = fmaf(wg, __uint_as_float(u & 0xffff0000u), acc1);
  };
  auto ld = [&](int2 q) -> unsigned {
    return *reinterpret_cast<const unsigned*>(
        h1c + (size_t)((unsigned)q.x & 0xFFFFFF00u));
  };

  const int wbeg = __builtin_amdgcn_readfirstlane(wb[w]);
  const int wend = __builtin_amdgcn_readfirstlane(wb[w + 1]);

  int k = wbeg;
  for (; k + 16 <= wend; k += 16) {
    int2 q[16]; unsigned u[16];
#pragma unroll
    for (int i = 0; i < 16; ++i) q[i] = colS2[k + i];
#pragma unroll
    for (int i = 0; i < 16; ++i) u[i] = ld(q[i]);
#pragma unroll
    for (int i = 0; i < 16; ++i) proc(q[i], u[i]);
  }
  for (; k + 4 <= wend; k += 4) {
    int2 q[4]; unsigned u[4];
#pragma unroll
    for (int i = 0; i < 4; ++i) q[i] = colS2[k + i];
#pragma unroll
    for (int i = 0; i < 4; ++i) u[i] = ld(q[i]);
#pragma unroll
    for (int i = 0; i < 4; ++i) proc(q[i], u[i]);
  }
  for (; k < wend; ++k) {
    const int2 q = colS2[k];
    proc(q, ld(q));
  }
  if (curRow >= 0) flush();
  __syncthreads();

  const float2 sc0 = *reinterpret_cast<const float2*>(&scale0[2 * l]);
  const float2 of0 = *reinterpret_cast<const float2*>(&offset0[2 * l]);
  const float2 sc1 = *reinterpret_cast<const float2*>(&scale1[2 * l]);
  const float2 of1 = *reinterpret_cast<const float2*>(&offset1[2 * l]);
  const float inv = 1.0f / 128.0f;
  for (int i = 0; i < 16; ++i) {
    const int node = rbase + (w << 4) + i;
    if (node >= N) break;
    const float2 hv = *reinterpret_cast<const float2*>(&h0[(size_t)node * D + 2 * l]);
    const float2 av = *reinterpret_cast<const float2*>(
        &aggL[((w << 4) + i) * ROWSTRIDE + 2 * l]);
    float sh = hv.x + hv.y, qh = hv.x * hv.x + hv.y * hv.y;
    float sa = av.x + av.y, qa = av.x * av.x + av.y * av.y;
#pragma unroll
    for (int o = 32; o; o >>= 1) {
      sh += __shfl_xor(sh, o, 64); qh += __shfl_xor(qh, o, 64);
      sa += __shfl_xor(sa, o, 64); qa += __shfl_xor(qa, o, 64);
    }
    const float m0 = sh * inv, v0 = qh * inv - m0 * m0 + 1e-9f;
    const float m1 = sa * inv, v1 = qa * inv - m1 * m1 + 1e-9f;
    const float r0 = rsqrtf(v0), r1 = rsqrtf(v1);
    float2 o2;
    o2.x = (hv.x - m0) * sc0.x * r0 + of0.x + (av.x - m1) * sc1.x * r1 + of1.x;
    o2.y = (hv.y - m0) * sc0.y * r0 + of0.y + (av.y - m1) * sc1.y * r1 + of1.y;
    *reinterpret_cast<float2*>(&out[(size_t)node * D + 2 * l]) = o2;
  }
}

// ---------------------------------------------------------------------------
extern "C" void kernel_launch(void* const* d_in, const int* in_sizes, int n_in,
                              void* d_out, int out_size, void* d_ws, size_t ws_size,
                              hipStream_t stream)
{
  const float* x       = (const float*)d_in[0];
  const int*   row     = (const int*)d_in[1];
  const int*   col     = (const int*)d_in[2];
  const float* W0      = (const float*)d_in[3];
  const float* b0      = (const float*)d_in[4];
  const float* W1      = (const float*)d_in[5];
  const float* b1      = (const float*)d_in[6];
  const float* att     = (const float*)d_in[7];
  const float* scale0  = (const float*)d_in[8];
  const float* offset0 = (const float*)d_in[9];
  const float* scale1  = (const float*)d_in[10];
  const float* offset1 = (const float*)d_in[11];

  const int N = in_sizes[0] / D;
  const int E = in_sizes[1];
  const int NBUK = (N + 63) >> BUCKET_SHIFT;

  char* ws = (char*)d_ws;
  size_t off = 0;
  auto alloc = [&](size_t bytes) -> void* {
    void* p = ws + off;
    off += (bytes + 511) & ~size_t(511);
    return p;
  };

  float*    h0      = (float*)d_out;                 // alias into d_out
  bf16*     h1b     = (bf16*)alloc((size_t)N * D * sizeof(bf16));
  float*    a_self  = (float*)alloc((size_t)N * sizeof(float));
  float*    a_neigh = (float*)alloc((size_t)N * sizeof(float));
  short*    Wb0     = (short*)alloc(16384 * sizeof(short));
  short*    Wb1     = (short*)alloc(16384 * sizeof(short));
  int*      bukCnt  = (int*)alloc((size_t)NBUK * sizeof(int));
  int*      runsW   = (int*)alloc((size_t)NBUK * 5 * sizeof(int));
  unsigned* buf1    = (unsigned*)alloc(((size_t)NBUK << BUCKET_CAP_LOG2) * sizeof(unsigned));
  int2*     colS2   = (int2*)alloc((size_t)E * sizeof(int2));

  hipMemsetAsync(bukCnt, 0, (size_t)NBUK * sizeof(int), stream);

  k_cvtW<<<128, 256, 0, stream>>>(W0, W1, Wb0, Wb1);
  dim3 ggrid((N + 63) / 64, 2);
  k_gemm<<<ggrid, 256, 0, stream>>>(x, Wb0, b0, Wb1, b1, att, h0, h1b,
                                    a_self, a_neigh, N);
  const int NBLKA = (E + 16383) / 16384;
  k_binA<<<NBLKA, 512, 0, stream>>>(row, col, bukCnt, buf1, E, NBUK);
  k_fine<<<NBUK, 256, 0, stream>>>(buf1, bukCnt, a_self, a_neigh,
                                   runsW, colS2, N);
  k_agg<<<NBUK, 256, 0, stream>>>(h0, h1b, runsW, colS2,
                                  scale0, offset0, scale1, offset1,
                                  (float*)d_out, N);
}

// Round 16
// 283.394 us; speedup vs baseline: 1.3748x; 1.0078x over previous
//
#include <hip/hip_runtime.h>
#include <hip/hip_bf16.h>

constexpr int D = 128;
constexpr int BUCKET_SHIFT = 6;        // 64 rows per bucket
constexpr int BUCKET_CAP_LOG2 = 12;    // 4096 slots per bucket (mean 2048)
constexpr int BUCKET_CAP = 1 << BUCKET_CAP_LOG2;
constexpr int SEG_SHIFT = 13;          // 8192 source rows per segment = 2MB bf16
constexpr int NSEG = 13;               // ceil(100000 / 8192)
constexpr int BINS_PER_BUCKET = 4 * NSEG * 16;   // (group, seg, rowloc) = 832
constexpr int BINS_PER_WAVE = NSEG * 16;         // 208
constexpr int ROWSTRIDE = 130;         // f32 LDS row stride
typedef __hip_bfloat16 bf16;
typedef __attribute__((ext_vector_type(8))) short bf16x8;
typedef __attribute__((ext_vector_type(4))) float f32x4;

__device__ __forceinline__ short f2b(float f) {
  bf16 h = __float2bfloat16(f);
  return *reinterpret_cast<short*>(&h);
}

// ---------------------------------------------------------------------------
// W f32 -> bf16 pre-conversion (64 KB total, one-shot).
// ---------------------------------------------------------------------------
__global__ void k_cvtW(const float* __restrict__ W0, const float* __restrict__ W1,
                       short* __restrict__ Wb0, short* __restrict__ Wb1)
{
  int i = blockIdx.x * 256 + threadIdx.x;
  if (i < 16384) Wb0[i] = f2b(W0[i]);
  else if (i < 32768) { int j = i - 16384; Wb1[j] = f2b(W1[j]); }
}

// ---------------------------------------------------------------------------
// MFMA GEMM + exact in-wave attention dots (proven round 14).
// ---------------------------------------------------------------------------
__global__ __launch_bounds__(256) void k_gemm(
    const float* __restrict__ x,
    const short* __restrict__ Wb0, const float* __restrict__ b0,
    const short* __restrict__ Wb1, const float* __restrict__ b1,
    const float* __restrict__ att,
    float* __restrict__ h0, bf16* __restrict__ h1b,
    float* __restrict__ a_self, float* __restrict__ a_neigh, int N)
{
  const int t = threadIdx.x;
  const int wv = t >> 6;
  const int l = t & 63;
  const int fb = blockIdx.y;
  const int nbase = blockIdx.x * 64 + wv * 16;
  const int lm = l & 15;      // A row / C-D col
  const int lk = l >> 4;      // K group (8 elems)

  const short* __restrict__ W    = fb ? Wb1 : Wb0;
  const float* __restrict__ bias = fb ? b1 : b0;
  const float* __restrict__ attp = att + fb * 128;

  f32x4 acc[8];
#pragma unroll
  for (int i = 0; i < 8; ++i) acc[i] = (f32x4){0.f, 0.f, 0.f, 0.f};

  const int node_a = nbase + lm;
  const bool okA = node_a < N;
  const float* xrow = x + (size_t)node_a * D + lk * 8;

#pragma unroll
  for (int ks = 0; ks < 4; ++ks) {
    float4 a0, a1;
    if (okA) {
      a0 = *reinterpret_cast<const float4*>(xrow + ks * 32);
      a1 = *reinterpret_cast<const float4*>(xrow + ks * 32 + 4);
    } else {
      a0 = make_float4(0.f, 0.f, 0.f, 0.f);
      a1 = a0;
    }
    bf16x8 af;
    af[0] = f2b(a0.x); af[1] = f2b(a0.y); af[2] = f2b(a0.z); af[3] = f2b(a0.w);
    af[4] = f2b(a1.x); af[5] = f2b(a1.y); af[6] = f2b(a1.z); af[7] = f2b(a1.w);
#pragma unroll
    for (int nt = 0; nt < 8; ++nt) {
      const bf16x8 bfr = *reinterpret_cast<const bf16x8*>(
          W + (size_t)(nt * 16 + lm) * D + ks * 32 + lk * 8);
      acc[nt] = __builtin_amdgcn_mfma_f32_16x16x32_bf16(af, bfr, acc[nt], 0, 0, 0);
    }
  }

  float pd[4] = {0.f, 0.f, 0.f, 0.f};
#pragma unroll
  for (int nt = 0; nt < 8; ++nt) {
    const int f = nt * 16 + lm;
    const float bv = bias[f];
    const float av = attp[f];
#pragma unroll
    for (int j = 0; j < 4; ++j) {
      const float r = fmaxf(acc[nt][j] + bv, 0.f);
      pd[j] = fmaf(r, av, pd[j]);
      const int ng = nbase + lk * 4 + j;
      if (ng < N) {
        if (fb == 0) h0[(size_t)ng * D + f] = r;
        else         h1b[(size_t)ng * D + f] = __float2bfloat16(r);
      }
    }
  }
#pragma unroll
  for (int m2 = 1; m2 < 16; m2 <<= 1) {
    pd[0] += __shfl_xor(pd[0], m2, 16);
    pd[1] += __shfl_xor(pd[1], m2, 16);
    pd[2] += __shfl_xor(pd[2], m2, 16);
    pd[3] += __shfl_xor(pd[3], m2, 16);
  }
  if (lm == 0) {
    float* __restrict__ adest = fb ? a_neigh : a_self;
#pragma unroll
    for (int j = 0; j < 4; ++j) {
      const int ng = nbase + lk * 4 + j;
      if (ng < N) adest[ng] = pd[j];
    }
  }
}

// ---------------------------------------------------------------------------
// Pass A: per-block LDS binning into fixed-capacity bucket regions (64 rows).
// ---------------------------------------------------------------------------
__global__ __launch_bounds__(512) void k_binA(
    const int* __restrict__ row, const int* __restrict__ col,
    int* __restrict__ bukCnt, unsigned* __restrict__ buf1, int E, int NBUK)
{
  constexpr int EPB = 16384;
  __shared__ int hist[1600];
  __shared__ int base[1600];
  const int t = threadIdx.x;
  const int e0 = blockIdx.x * EPB;
  const int e1 = min(e0 + EPB, E);

  for (int i = t; i < NBUK; i += 512) hist[i] = 0;
  __syncthreads();
  for (int e = e0 + t; e < e1; e += 512)
    atomicAdd(&hist[row[e] >> BUCKET_SHIFT], 1);
  __syncthreads();
  for (int bk = t; bk < NBUK; bk += 512) {
    int c = hist[bk];
    base[bk] = (c > 0) ? atomicAdd(&bukCnt[bk], c) : 0;
  }
  __syncthreads();
  for (int i = t; i < NBUK; i += 512) hist[i] = 0;
  __syncthreads();
  for (int e = e0 + t; e < e1; e += 512) {
    int r = row[e];
    int c = col[e];
    int bk = r >> BUCKET_SHIFT;
    int pos = base[bk] + atomicAdd(&hist[bk], 1);
    if (pos < BUCKET_CAP)   // statistically never taken; OOB guard
      buf1[((size_t)bk << BUCKET_CAP_LOG2) + pos] =
          ((unsigned)c << BUCKET_SHIFT) | (unsigned)(r & 63);
  }
}

// ---------------------------------------------------------------------------
// Pass B: one block per bucket. Bins edges by (rowgroup, seg, rowloc) so the
// edge array is contiguous, seg-major and row-sorted per wave-group range.
// Emits gather-ready int2 { (col<<8)|rowloc, wg } with the COMPLETE edge
// weight wg = lrelu(a_self[r]) + lrelu(a_neigh[c]) fused. Self-computes its
// global compaction base; writes only the 5 wave boundaries per bucket.
// ---------------------------------------------------------------------------
__global__ __launch_bounds__(256) void k_fine(
    const unsigned* __restrict__ buf1,
    const int* __restrict__ bukCnt,
    const float* __restrict__ a_self, const float* __restrict__ a_neigh,
    int* __restrict__ runsW, int2* __restrict__ colS2, int N)
{
  __shared__ int lhist[BINS_PER_BUCKET], labs[BINS_PER_BUCKET], lcur[BINS_PER_BUCKET];
  __shared__ float asF[64];
  __shared__ int sd[256];
  __shared__ int gbS;
  const int b = blockIdx.x;
  const int t = threadIdx.x;
  const int n = min(bukCnt[b], BUCKET_CAP);
  const unsigned* src = buf1 + ((size_t)b << BUCKET_CAP_LOG2);
  const int rstart = b << BUCKET_SHIFT;

  // ---- self-computed compaction base gb = sum_{i<b} min(bukCnt[i],CAP) ----
  int pre = 0;
  for (int i = t; i < b; i += 256) pre += min(bukCnt[i], BUCKET_CAP);
  sd[t] = pre;
  __syncthreads();
  for (int d2 = 128; d2 > 0; d2 >>= 1) {
    if (t < d2) sd[t] += sd[t + d2];
    __syncthreads();
  }
  if (t == 0) gbS = sd[0];

  for (int i = t; i < BINS_PER_BUCKET; i += 256) { lhist[i] = 0; lcur[i] = 0; }
  if (t < 64) {
    float v = (rstart + t < N) ? a_self[rstart + t] : 0.f;
    asF[t] = v > 0.f ? v : 0.2f * v;
  }
  __syncthreads();
  const int gb = gbS;

  // histogram by (group, seg, rowloc)
  for (int i = t; i < n; i += 256) {
    unsigned e = src[i];
    int r = e & 63, c = e >> BUCKET_SHIFT;
    int bin = (((r >> 4) * NSEG) + (c >> SEG_SHIFT)) * 16 + (r & 15);
    atomicAdd(&lhist[bin], 1);
  }
  __syncthreads();
  // exclusive scan (4 bins/thread)
  int v[4], s = 0;
  const int bin0 = t * 4;
#pragma unroll
  for (int i = 0; i < 4; ++i) {
    v[i] = (bin0 + i < BINS_PER_BUCKET) ? lhist[bin0 + i] : 0;
    s += v[i];
  }
  sd[t] = s;
  __syncthreads();
  for (int d2 = 1; d2 < 256; d2 <<= 1) {
    int o = (t >= d2) ? sd[t - d2] : 0;
    __syncthreads();
    sd[t] += o;
    __syncthreads();
  }
  int excl = sd[t] - s;
#pragma unroll
  for (int i = 0; i < 4; ++i) {
    if (bin0 + i < BINS_PER_BUCKET) labs[bin0 + i] = gb + excl;
    excl += v[i];
  }
  __syncthreads();
  // wave boundaries only (k_agg reads exactly these 5)
  if (t < 4) runsW[b * 5 + t] = labs[t * BINS_PER_WAVE];
  else if (t == 4) runsW[b * 5 + 4] = gb + n;
  // scatter, weight-fused
  for (int i = t; i < n; i += 256) {
    unsigned e = src[i];
    int r = e & 63, c = e >> BUCKET_SHIFT;
    int bin = (((r >> 4) * NSEG) + (c >> SEG_SHIFT)) * 16 + (r & 15);
    int pos = labs[bin] + atomicAdd(&lcur[bin], 1);
    float an = a_neigh[c];
    an = an > 0.f ? an : 0.2f * an;
    colS2[pos] = make_int2((c << 8) | r, __float_as_int(asF[r] + an));
  }
}

// ---------------------------------------------------------------------------
// Segment-swept aggregate, stageless (round-15 inner loop, HALVED geometry):
// block = 2 waves / 32 rows (half-bucket selected by blockIdx&1) -> aggL
// 16.6 KB -> ~9 blocks/CU by LDS (occupancy ~2x round 15). Wave g=h*2+w owns
// bucket rows g*16..g*16+15 and one CONTIGUOUS seg-major edge range; edge
// entries read directly from global at wave-uniform indices; 16-deep batched
// h1 gathers; register accumulate per row, LDS flush on row change.
// NOTE: h0 aliases d_out; block reads only its own rows, then overwrites them.
// ---------------------------------------------------------------------------
__global__ __launch_bounds__(128) void k_agg(
    const float* __restrict__ h0, const bf16* __restrict__ h1b,
    const int* __restrict__ runsW, const int2* __restrict__ colS2,
    const float* __restrict__ scale0, const float* __restrict__ offset0,
    const float* __restrict__ scale1, const float* __restrict__ offset1,
    float* __restrict__ out, int N)
{
  __shared__ float aggL[32 * ROWSTRIDE];          // 16.6 KB accumulator
  __shared__ int wb[3];                           // wave range boundaries
  const int b2 = blockIdx.x;
  const int bk = b2 >> 1, h = b2 & 1;
  const int t = threadIdx.x;
  const int w = t >> 6, l = t & 63;               // w in {0,1}
  const int rbase = (bk << 6) + (h << 5);

  for (int i = t; i < 32 * ROWSTRIDE; i += 128) aggL[i] = 0.f;
  if (t < 3) wb[t] = runsW[bk * 5 + h * 2 + t];
  __syncthreads();

  const char* h1c = reinterpret_cast<const char*>(h1b) + l * 4;
  float acc0 = 0.f, acc1 = 0.f;
  int curRow = -1;   // bucket-local row id (0..63)

  auto flush = [&]() {
    float* pp = &aggL[(curRow & 31) * ROWSTRIDE + 2 * l];
    const float2 o = *reinterpret_cast<const float2*>(pp);
    *reinterpret_cast<float2*>(pp) = make_float2(o.x + acc0, o.y + acc1);
  };
  auto proc = [&](int2 q, unsigned u) {
    const int r_ = q.x & 63;
    if (r_ != curRow) {
      if (curRow >= 0) flush();
      acc0 = 0.f; acc1 = 0.f; curRow = r_;
    }
    const float wg = __int_as_float(q.y);
    acc0 = fmaf(wg, __uint_as_float(u << 16), acc0);
    acc1 = fmaf(wg, __uint_as_float(u & 0xffff0000u), acc1);
  };
  auto ld = [&](int2 q) -> unsigned {
    return *reinterpret_cast<const unsigned*>(
        h1c + (size_t)((unsigned)q.x & 0xFFFFFF00u));
  };

  const int wbeg = __builtin_amdgcn_readfirstlane(wb[w]);
  const int wend = __builtin_amdgcn_readfirstlane(wb[w + 1]);

  int k = wbeg;
  for (; k + 16 <= wend; k += 16) {
    int2 q[16]; unsigned u[16];
#pragma unroll
    for (int i = 0; i < 16; ++i) q[i] = colS2[k + i];
#pragma unroll
    for (int i = 0; i < 16; ++i) u[i] = ld(q[i]);
#pragma unroll
    for (int i = 0; i < 16; ++i) proc(q[i], u[i]);
  }
  for (; k + 4 <= wend; k += 4) {
    int2 q[4]; unsigned u[4];
#pragma unroll
    for (int i = 0; i < 4; ++i) q[i] = colS2[k + i];
#pragma unroll
    for (int i = 0; i < 4; ++i) u[i] = ld(q[i]);
#pragma unroll
    for (int i = 0; i < 4; ++i) proc(q[i], u[i]);
  }
  for (; k < wend; ++k) {
    const int2 q = colS2[k];
    proc(q, ld(q));
  }
  if (curRow >= 0) flush();
  __syncthreads();

  const float2 sc0 = *reinterpret_cast<const float2*>(&scale0[2 * l]);
  const float2 of0 = *reinterpret_cast<const float2*>(&offset0[2 * l]);
  const float2 sc1 = *reinterpret_cast<const float2*>(&scale1[2 * l]);
  const float2 of1 = *reinterpret_cast<const float2*>(&offset1[2 * l]);
  const float inv = 1.0f / 128.0f;
  for (int i = 0; i < 16; ++i) {
    const int rl = (w << 4) + i;                  // block-local row (0..31)
    const int node = rbase + rl;
    if (node >= N) break;
    const float2 hv = *reinterpret_cast<const float2*>(&h0[(size_t)node * D + 2 * l]);
    const float2 av = *reinterpret_cast<const float2*>(&aggL[rl * ROWSTRIDE + 2 * l]);
    float sh = hv.x + hv.y, qh = hv.x * hv.x + hv.y * hv.y;
    float sa = av.x + av.y, qa = av.x * av.x + av.y * av.y;
#pragma unroll
    for (int o = 32; o; o >>= 1) {
      sh += __shfl_xor(sh, o, 64); qh += __shfl_xor(qh, o, 64);
      sa += __shfl_xor(sa, o, 64); qa += __shfl_xor(qa, o, 64);
    }
    const float m0 = sh * inv, v0 = qh * inv - m0 * m0 + 1e-9f;
    const float m1 = sa * inv, v1 = qa * inv - m1 * m1 + 1e-9f;
    const float r0 = rsqrtf(v0), r1 = rsqrtf(v1);
    float2 o2;
    o2.x = (hv.x - m0) * sc0.x * r0 + of0.x + (av.x - m1) * sc1.x * r1 + of1.x;
    o2.y = (hv.y - m0) * sc0.y * r0 + of0.y + (av.y - m1) * sc1.y * r1 + of1.y;
    *reinterpret_cast<float2*>(&out[(size_t)node * D + 2 * l]) = o2;
  }
}

// ---------------------------------------------------------------------------
extern "C" void kernel_launch(void* const* d_in, const int* in_sizes, int n_in,
                              void* d_out, int out_size, void* d_ws, size_t ws_size,
                              hipStream_t stream)
{
  const float* x       = (const float*)d_in[0];
  const int*   row     = (const int*)d_in[1];
  const int*   col     = (const int*)d_in[2];
  const float* W0      = (const float*)d_in[3];
  const float* b0      = (const float*)d_in[4];
  const float* W1      = (const float*)d_in[5];
  const float* b1      = (const float*)d_in[6];
  const float* att     = (const float*)d_in[7];
  const float* scale0  = (const float*)d_in[8];
  const float* offset0 = (const float*)d_in[9];
  const float* scale1  = (const float*)d_in[10];
  const float* offset1 = (const float*)d_in[11];

  const int N = in_sizes[0] / D;
  const int E = in_sizes[1];
  const int NBUK = (N + 63) >> BUCKET_SHIFT;

  char* ws = (char*)d_ws;
  size_t off = 0;
  auto alloc = [&](size_t bytes) -> void* {
    void* p = ws + off;
    off += (bytes + 511) & ~size_t(511);
    return p;
  };

  float*    h0      = (float*)d_out;                 // alias into d_out
  bf16*     h1b     = (bf16*)alloc((size_t)N * D * sizeof(bf16));
  float*    a_self  = (float*)alloc((size_t)N * sizeof(float));
  float*    a_neigh = (float*)alloc((size_t)N * sizeof(float));
  short*    Wb0     = (short*)alloc(16384 * sizeof(short));
  short*    Wb1     = (short*)alloc(16384 * sizeof(short));
  int*      bukCnt  = (int*)alloc((size_t)NBUK * sizeof(int));
  int*      runsW   = (int*)alloc((size_t)NBUK * 5 * sizeof(int));
  unsigned* buf1    = (unsigned*)alloc(((size_t)NBUK << BUCKET_CAP_LOG2) * sizeof(unsigned));
  int2*     colS2   = (int2*)alloc((size_t)E * sizeof(int2));

  hipMemsetAsync(bukCnt, 0, (size_t)NBUK * sizeof(int), stream);

  k_cvtW<<<128, 256, 0, stream>>>(W0, W1, Wb0, Wb1);
  dim3 ggrid((N + 63) / 64, 2);
  k_gemm<<<ggrid, 256, 0, stream>>>(x, Wb0, b0, Wb1, b1, att, h0, h1b,
                                    a_self, a_neigh, N);
  const int NBLKA = (E + 16383) / 16384;
  k_binA<<<NBLKA, 512, 0, stream>>>(row, col, bukCnt, buf1, E, NBUK);
  k_fine<<<NBUK, 256, 0, stream>>>(buf1, bukCnt, a_self, a_neigh,
                                   runsW, colS2, N);
  k_agg<<<NBUK * 2, 128, 0, stream>>>(h0, h1b, runsW, colS2,
                                      scale0, offset0, scale1, offset1,
                                      (float*)d_out, N);
}